// Round 4
// baseline (279.532 us; speedup 1.0000x reference)
//
#include <hip/hip_runtime.h>
#include <cstdint>

// Problem constants
#define NB   32      // batch
#define NC   256     // z channels
#define NE   128     // embed dim
#define NS   256     // H*W pixels per batch
#define NV   4096    // vocab
#define NP   8192    // total pixels
#define NSPLIT 4     // vocab splits for score_argmax

// ---- dtype forensics (rounds 0-3): inputs fp32 AND outputs fp32.
// Rounds 1&3 (bf16 output writes) gave identical error 2.21875 == max|z[i]-z[2i+1]|
// of two bf16 packed into one f32 word => output buffer is decoded as fp32.
// Round 2 (bf16 input reads) gave NaN => inputs are fp32 bits.

#define DOT4F(acc, a, bb) \
    acc = fmaf((a).x, (bb).x, fmaf((a).y, (bb).y, fmaf((a).z, (bb).z, fmaf((a).w, (bb).w, acc))))

// ---------------------------------------------------------------------------
// K1: z = pre_w @ z_e + pre_b   (per batch: (128x256)@(256x256)), fp32.
// grid (8 e-tiles, 32 batches), 256 threads (one pixel s each), 16 e each.
// ---------------------------------------------------------------------------
__global__ __launch_bounds__(256) void pre_conv(
    const float* __restrict__ z_e, const float* __restrict__ pre_w,
    const float* __restrict__ pre_b, float* __restrict__ out_z)
{
    __shared__ __align__(16) float wlds[16 * 256];
    const int t  = threadIdx.x;
    const int e0 = blockIdx.x * 16;
    const int b  = blockIdx.y;

    for (int idx = t; idx < 16 * 256; idx += 256) {
        int r = idx >> 8, c = idx & 255;
        wlds[r * 256 + c] = pre_w[(e0 + r) * 256 + c];
    }
    __syncthreads();

    const int s = t;
    float acc[16];
#pragma unroll
    for (int r = 0; r < 16; r++) acc[r] = pre_b[e0 + r];

    const float* zin = z_e + (size_t)(b * NC) * NS + s;
    for (int c = 0; c < NC; c += 4) {
        float z0 = zin[(c + 0) * NS];
        float z1 = zin[(c + 1) * NS];
        float z2 = zin[(c + 2) * NS];
        float z3 = zin[(c + 3) * NS];
#pragma unroll
        for (int r = 0; r < 16; r++) {
            float4 w = *(const float4*)&wlds[r * 256 + c];
            acc[r] = fmaf(z0, w.x, fmaf(z1, w.y, fmaf(z2, w.z, fmaf(z3, w.w, acc[r]))));
        }
    }
#pragma unroll
    for (int r = 0; r < 16; r++)
        out_z[(size_t)(b * NE + e0 + r) * NS + s] = acc[r];
}

// ---------------------------------------------------------------------------
// K2: cnorm[v] = 0.5 * |emb[v]|^2
// ---------------------------------------------------------------------------
__global__ __launch_bounds__(256) void code_norm(
    const float* __restrict__ emb, float* __restrict__ cnorm)
{
    const int v = blockIdx.x * 256 + threadIdx.x;
    const float4* row = (const float4*)(emb + (size_t)v * NE);
    float s = 0.f;
#pragma unroll
    for (int k = 0; k < NE / 4; k++) {
        float4 x = row[k];
        s = fmaf(x.x, x.x, fmaf(x.y, x.y, fmaf(x.z, x.z, fmaf(x.w, x.w, s))));
    }
    cnorm[v] = 0.5f * s;
}

// ---------------------------------------------------------------------------
// K3: score = z.c - 0.5|c|^2 (== argmin of distance), running argmax over
// this block's vocab split. Tile 64 px x 64 codes; k in two 64-halves so
// static LDS = 33.8 + 17.4 KB < 64 KB limit.
// Thread map: cg = t&15 -> codes {cg, cg+16, cg+32, cg+48}; pg = t>>4 -> 4 px.
// ---------------------------------------------------------------------------
__global__ __launch_bounds__(256) void score_argmax(
    const float* __restrict__ z, const float* __restrict__ emb,
    const float* __restrict__ cnorm,
    float* __restrict__ pscore, int* __restrict__ pidx)
{
    __shared__ __align__(16) float As[64 * 132];   // px x 128k, padded
    __shared__ __align__(16) float Bs[64 * 68];    // codes x 64k half, padded

    const int t     = threadIdx.x;
    const int ptile = blockIdx.x;       // 0..127
    const int split = blockIdx.y;       // 0..NSPLIT-1
    const int p0 = ptile * 64;
    const int b  = p0 >> 8;
    const int s0 = p0 & 255;

    // Stage A: 64 px x 128 k (coalesced along s)
    for (int idx = t; idx < 64 * 128; idx += 256) {
        int k = idx >> 6, i = idx & 63;
        As[i * 132 + k] = z[(size_t)(b * NE + k) * NS + s0 + i];
    }

    const int cg = t & 15;
    const int pg = t >> 4;
    const float* Ap = &As[(pg * 4) * 132];

    float best[4];
    int   bidx_[4];
#pragma unroll
    for (int pp = 0; pp < 4; pp++) { best[pp] = -1e30f; bidx_[pp] = 0; }

    const int vbase = split * (NV / NSPLIT);
    const float4* emb4 = (const float4*)emb;   // 32 float4 per code row

    for (int vt = 0; vt < (NV / NSPLIT) / 64; vt++) {
        float acc[4][4];
#pragma unroll
        for (int pp = 0; pp < 4; pp++)
#pragma unroll
            for (int cc = 0; cc < 4; cc++) acc[pp][cc] = 0.f;

        const int crow0 = vbase + vt * 64;
#pragma unroll
        for (int half = 0; half < 2; half++) {
            __syncthreads();   // protect Bs (and, first iter, publish As)
            for (int idx = t; idx < 64 * 16; idx += 256) {
                int j = idx >> 4, k4 = idx & 15;
                float4 v = emb4[(size_t)(crow0 + j) * 32 + half * 16 + k4];
                *(float4*)&Bs[j * 68 + k4 * 4] = v;
            }
            __syncthreads();

            const float* Bp = &Bs[cg * 68];
            const float* Ah = Ap + half * 64;
#pragma unroll 4
            for (int k = 0; k < 64; k += 4) {
                float4 a0 = *(const float4*)(Ah + 0 * 132 + k);
                float4 a1 = *(const float4*)(Ah + 1 * 132 + k);
                float4 a2 = *(const float4*)(Ah + 2 * 132 + k);
                float4 a3 = *(const float4*)(Ah + 3 * 132 + k);
                float4 b0 = *(const float4*)(Bp +  0 * 68 + k);
                float4 b1 = *(const float4*)(Bp + 16 * 68 + k);
                float4 b2 = *(const float4*)(Bp + 32 * 68 + k);
                float4 b3 = *(const float4*)(Bp + 48 * 68 + k);
                DOT4F(acc[0][0], a0, b0); DOT4F(acc[0][1], a0, b1);
                DOT4F(acc[0][2], a0, b2); DOT4F(acc[0][3], a0, b3);
                DOT4F(acc[1][0], a1, b0); DOT4F(acc[1][1], a1, b1);
                DOT4F(acc[1][2], a1, b2); DOT4F(acc[1][3], a1, b3);
                DOT4F(acc[2][0], a2, b0); DOT4F(acc[2][1], a2, b1);
                DOT4F(acc[2][2], a2, b2); DOT4F(acc[2][3], a2, b3);
                DOT4F(acc[3][0], a3, b0); DOT4F(acc[3][1], a3, b1);
                DOT4F(acc[3][2], a3, b2); DOT4F(acc[3][3], a3, b3);
            }
        }

        const int c0 = crow0 + cg;   // this thread's codes: c0 + 16*cc
        float cn[4] = { cnorm[c0], cnorm[c0 + 16], cnorm[c0 + 32], cnorm[c0 + 48] };
#pragma unroll
        for (int pp = 0; pp < 4; pp++) {
#pragma unroll
            for (int cc = 0; cc < 4; cc++) {
                float sc = acc[pp][cc] - cn[cc];
                if (sc > best[pp]) { best[pp] = sc; bidx_[pp] = c0 + 16 * cc; }
            }
        }
    }

    __syncthreads();
    // Cross-thread reduction over 16 code groups; reuse As as scratch.
    float2* red = (float2*)As;   // [64 px][16 cg]
#pragma unroll
    for (int pp = 0; pp < 4; pp++)
        red[(pg * 4 + pp) * 16 + cg] = make_float2(best[pp], __int_as_float(bidx_[pp]));
    __syncthreads();

    if (t < 64) {
        float bs = -1e30f;
        int   bi = 0x7fffffff;
        for (int c = 0; c < 16; c++) {
            float2 e = red[t * 16 + c];
            int ii = __float_as_int(e.y);
            if (e.x > bs || (e.x == bs && ii < bi)) { bs = e.x; bi = ii; }
        }
        const int p = p0 + t;
        pscore[split * NP + p] = bs;
        pidx[split * NP + p]   = bi;
    }
}

// ---------------------------------------------------------------------------
// K4: merge NSPLIT candidates (tie -> lowest index == np.argmin semantics),
// gather z_q = emb[token] (exact fp32 copy), layout (b,e,s).
// ---------------------------------------------------------------------------
__global__ __launch_bounds__(256) void merge_gather(
    const float* __restrict__ pscore, const int* __restrict__ pidx,
    const float* __restrict__ emb, float* __restrict__ out_zq)
{
    __shared__ int tok_l[64];
    const int t  = threadIdx.x;
    const int p0 = blockIdx.x * 64;
    const int b  = p0 >> 8;
    const int s0 = p0 & 255;

    if (t < 64) {
        const int p = p0 + t;
        float bs = -1e30f;
        int   bi = 0x7fffffff;
#pragma unroll
        for (int sp = 0; sp < NSPLIT; sp++) {
            float sc = pscore[sp * NP + p];
            int   ii = pidx[sp * NP + p];
            if (sc > bs || (sc == bs && ii < bi)) { bs = sc; bi = ii; }
        }
        tok_l[t] = bi;
    }
    __syncthreads();

    for (int idx = t; idx < NE * 64; idx += 256) {
        int e = idx >> 6, i = idx & 63;
        out_zq[(size_t)(b * NE + e) * NS + s0 + i] = emb[(size_t)tok_l[i] * NE + e];
    }
}

// ---------------------------------------------------------------------------
// K5: rec = post_w @ z_q + post_b  (per batch: (256x128)@(128x256)), fp32.
// dec_in = z + stopgrad(z_q - z) == z_q in forward value.
// Overwrites the scratch region (cnorm/pscore/pidx already consumed).
// ---------------------------------------------------------------------------
__global__ __launch_bounds__(256) void post_conv(
    const float* __restrict__ zq, const float* __restrict__ post_w,
    const float* __restrict__ post_b, float* __restrict__ out_rec)
{
    __shared__ __align__(16) float wlds[16 * 128];
    const int t  = threadIdx.x;
    const int c0 = blockIdx.x * 16;
    const int b  = blockIdx.y;

    for (int idx = t; idx < 16 * 128; idx += 256) {
        int r = idx >> 7, e = idx & 127;
        wlds[r * 128 + e] = post_w[(c0 + r) * 128 + e];
    }
    __syncthreads();

    const int s = t;
    float acc[16];
#pragma unroll
    for (int r = 0; r < 16; r++) acc[r] = post_b[c0 + r];

    const float* zin = zq + (size_t)(b * NE) * NS + s;
    for (int e = 0; e < NE; e += 4) {
        float z0 = zin[(e + 0) * NS];
        float z1 = zin[(e + 1) * NS];
        float z2 = zin[(e + 2) * NS];
        float z3 = zin[(e + 3) * NS];
#pragma unroll
        for (int r = 0; r < 16; r++) {
            float4 w = *(const float4*)&wlds[r * 128 + e];
            acc[r] = fmaf(z0, w.x, fmaf(z1, w.y, fmaf(z2, w.z, fmaf(z3, w.w, acc[r]))));
        }
    }
#pragma unroll
    for (int r = 0; r < 16; r++)
        out_rec[(size_t)(b * NC + c0 + r) * NS + s] = acc[r];
}

// ---------------------------------------------------------------------------
extern "C" void kernel_launch(void* const* d_in, const int* in_sizes, int n_in,
                              void* d_out, int out_size, void* d_ws, size_t ws_size,
                              hipStream_t stream)
{
    const float* z_e    = (const float*)d_in[0];  // (32,256,16,16) fp32
    const float* pre_w  = (const float*)d_in[1];  // (128,256) fp32
    const float* pre_b  = (const float*)d_in[2];  // (128) fp32
    const float* emb    = (const float*)d_in[3];  // (4096,128) fp32
    const float* post_w = (const float*)d_in[4];  // (256,128) fp32
    const float* post_b = (const float*)d_in[5];  // (256) fp32

    // d_out: fp32 x 4194304 = (z 1048576 | z_q 1048576 | rec 2097152)
    float* out    = (float*)d_out;
    float* out_z  = out;                 // final z
    float* out_zq = out + 1048576;       // final z_q
    float* out_rec= out + 2097152;       // scratch head, then final rec

    // Scratch inside the rec region (272 KB of its 8 MB), overwritten by K5:
    float* cnorm  = out_rec;                       // 4096 fp32
    float* pscore = out_rec + 4096;                // NSPLIT*NP fp32
    int*   pidx   = (int*)(out_rec + 4096 + NSPLIT * NP);

    pre_conv    <<<dim3(8, 32),       256, 0, stream>>>(z_e, pre_w, pre_b, out_z);
    code_norm   <<<dim3(16),          256, 0, stream>>>(emb, cnorm);
    score_argmax<<<dim3(128, NSPLIT), 256, 0, stream>>>(out_z, emb, cnorm, pscore, pidx);
    merge_gather<<<dim3(128),         256, 0, stream>>>(pscore, pidx, emb, out_zq);
    post_conv   <<<dim3(16, 32),      256, 0, stream>>>(out_zq, post_w, post_b, out_rec);
}

// Round 6
// 177.596 us; speedup vs baseline: 1.5740x; 1.5740x over previous
//
#include <hip/hip_runtime.h>
#include <hip/hip_bf16.h>
#include <cstdint>

// Problem constants
#define NB   32      // batch
#define NC   256     // z channels
#define NE   128     // embed dim
#define NS   256     // H*W pixels per batch
#define NV   4096    // vocab
#define NP   8192    // total pixels
#define NSPLIT 4     // vocab splits for score kernel

typedef unsigned short ushort_t;
typedef __attribute__((ext_vector_type(8))) short bf16x8;           // MFMA A/B frag
typedef __attribute__((ext_vector_type(8))) unsigned short us8;     // pack store
typedef __attribute__((ext_vector_type(4))) float f32x4;            // MFMA C/D frag

__device__ __forceinline__ float bf2f(ushort_t u) {
    union { unsigned int i; float f; } x; x.i = ((unsigned int)u) << 16; return x.f;
}
__device__ __forceinline__ ushort_t f2bf(float f) {
    __hip_bfloat16 h = __float2bfloat16(f);
    ushort_t u; __builtin_memcpy(&u, &h, 2); return u;
}

// ---------------------------------------------------------------------------
// K1: z = pre_w @ z_e + pre_b (fp32) -> out_z only. (Validated in round 4.)
// ---------------------------------------------------------------------------
__global__ __launch_bounds__(256) void pre_conv(
    const float* __restrict__ z_e, const float* __restrict__ pre_w,
    const float* __restrict__ pre_b, float* __restrict__ out_z)
{
    __shared__ __align__(16) float wlds[16 * 256];
    const int t  = threadIdx.x;
    const int e0 = blockIdx.x * 16;
    const int b  = blockIdx.y;

    for (int idx = t; idx < 16 * 256; idx += 256) {
        int r = idx >> 8, c = idx & 255;
        wlds[r * 256 + c] = pre_w[(e0 + r) * 256 + c];
    }
    __syncthreads();

    const int s = t;
    float acc[16];
#pragma unroll
    for (int r = 0; r < 16; r++) acc[r] = pre_b[e0 + r];

    const float* zin = z_e + (size_t)(b * NC) * NS + s;
    for (int c = 0; c < NC; c += 4) {
        float z0 = zin[(c + 0) * NS];
        float z1 = zin[(c + 1) * NS];
        float z2 = zin[(c + 2) * NS];
        float z3 = zin[(c + 3) * NS];
#pragma unroll
        for (int r = 0; r < 16; r++) {
            float4 w = *(const float4*)&wlds[r * 256 + c];
            acc[r] = fmaf(z0, w.x, fmaf(z1, w.y, fmaf(z2, w.z, fmaf(z3, w.w, acc[r]))));
        }
    }
#pragma unroll
    for (int r = 0; r < 16; r++)
        out_z[(size_t)(b * NE + e0 + r) * NS + s] = acc[r];
}

// ---------------------------------------------------------------------------
// K2: pack emb into Bpack (hi/lo bf16, MFMA B-frag order) + cnorm.
// Bpack layout (ushort units): [(G*2+plane)*4 + ks]*512 + L*8 + j
//   element = emb[code = G*16 + (L&15)][k = ks*32 + (L>>4)*8 + j]
// ---------------------------------------------------------------------------
__global__ __launch_bounds__(256) void pack_b(
    const float* __restrict__ emb, ushort_t* __restrict__ Bpack,
    float* __restrict__ cnorm)
{
    const int t = threadIdx.x;
    if (t >= 128) return;
    const int v = blockIdx.x * 128 + t;
    const float* row = emb + (size_t)v * NE;
    const int G = v >> 4;
    float nn = 0.f;
#pragma unroll
    for (int ks = 0; ks < 4; ks++) {
#pragma unroll
        for (int q = 0; q < 4; q++) {
            us8 hv, lv;
#pragma unroll
            for (int j = 0; j < 8; j++) {
                float x = row[ks * 32 + q * 8 + j];
                nn = fmaf(x, x, nn);
                ushort_t h = f2bf(x);
                hv[j] = h;
                lv[j] = f2bf(x - bf2f(h));
            }
            const int L = (v & 15) | (q << 4);
            *(us8*)(Bpack + ((size_t)(G * 2 + 0) * 4 + ks) * 512 + L * 8) = hv;
            *(us8*)(Bpack + ((size_t)(G * 2 + 1) * 4 + ks) * 512 + L * 8) = lv;
        }
    }
    cnorm[v] = 0.5f * nn;
}

// ---------------------------------------------------------------------------
// K3: MFMA score filter. Block = (64-px set) x (split of 1024 codes); 4 waves
// each take 256 codes. A-frags built IN-KERNEL from out_z via LDS (no Apack
// scratch); B-frags streamed from Bpack (d_ws, L2-resident). 3-term hi/lo
// bf16 MFMA into fp32; per-lane top-2 -> block top-2 per split -> pidx2.
// LDS: union { A-stage 33.8 KB | reduction 48 KB }.
// ---------------------------------------------------------------------------
__global__ __launch_bounds__(256, 2) void score_mfma(
    const float* __restrict__ z, const ushort_t* __restrict__ Bpack,
    const float* __restrict__ cnorm, int* __restrict__ pidx2)
{
    __shared__ __align__(16) char smraw[49152];
    float*    As  = (float*)smraw;            // 64 x 132 (staging)
    float*    s1l = (float*)smraw;            // 4096 (reduction, reused)
    float*    s2l = (float*)(smraw + 16384);
    unsigned* iil = (unsigned*)(smraw + 32768);

    const int t = threadIdx.x;
    const int wave = t >> 6, lane = t & 63;
    const int set = blockIdx.x;      // 0..127
    const int split = blockIdx.y;    // 0..3
    const int p0 = set * 64;
    const int b  = p0 >> 8;
    const int s0 = p0 & 255;

    // Stage A tile: 64 px x 128 k fp32 (coalesced along s)
    for (int idx = t; idx < 64 * 128; idx += 256) {
        int k = idx >> 6, i = idx & 63;
        As[i * 132 + k] = z[(size_t)(b * NE + k) * NS + s0 + i];
    }
    __syncthreads();

    // Build A fragments hi/lo in registers (4 mtiles x 4 ksteps -> 128 VGPRs)
    bf16x8 ah[4][4], al[4][4];
    const int am = lane & 15, aq = lane >> 4;
#pragma unroll
    for (int mt = 0; mt < 4; mt++)
#pragma unroll
        for (int ks = 0; ks < 4; ks++) {
            const float* src = As + (mt * 16 + am) * 132 + ks * 32 + aq * 8;
            float4 x0 = *(const float4*)src;
            float4 x1 = *(const float4*)(src + 4);
            float xv[8] = { x0.x, x0.y, x0.z, x0.w, x1.x, x1.y, x1.z, x1.w };
            bf16x8 hv, lv;
#pragma unroll
            for (int j = 0; j < 8; j++) {
                ushort_t h = f2bf(xv[j]);
                hv[j] = (short)h;
                lv[j] = (short)f2bf(xv[j] - bf2f(h));
            }
            ah[mt][ks] = hv;
            al[mt][ks] = lv;
        }
    __syncthreads();   // all As reads done before LDS reuse below

    float b1v[16], b2v[16]; unsigned i12[16];
#pragma unroll
    for (int i = 0; i < 16; i++) { b1v[i] = -1e30f; b2v[i] = -1e30f; i12[i] = 0u; }

    const int cg_base = split * 64 + wave * 16;

    for (int cgi = 0; cgi < 16; cgi++) {
        const int cg = cg_base + cgi;
        const ushort_t* bp = Bpack + (size_t)cg * 4096;
        bf16x8 bh[4], bl[4];
#pragma unroll
        for (int ks = 0; ks < 4; ks++) {
            bh[ks] = *(const bf16x8*)(bp + ks * 512 + lane * 8);
            bl[ks] = *(const bf16x8*)(bp + 2048 + ks * 512 + lane * 8);
        }
        const int code = cg * 16 + (lane & 15);
        const float cn = cnorm[code];

        f32x4 acc[4];
#pragma unroll
        for (int mt = 0; mt < 4; mt++) acc[mt] = (f32x4){0.f, 0.f, 0.f, 0.f};

#pragma unroll
        for (int ks = 0; ks < 4; ks++) {
#pragma unroll
            for (int mt = 0; mt < 4; mt++)
                acc[mt] = __builtin_amdgcn_mfma_f32_16x16x32_bf16(ah[mt][ks], bh[ks], acc[mt], 0, 0, 0);
#pragma unroll
            for (int mt = 0; mt < 4; mt++)
                acc[mt] = __builtin_amdgcn_mfma_f32_16x16x32_bf16(ah[mt][ks], bl[ks], acc[mt], 0, 0, 0);
#pragma unroll
            for (int mt = 0; mt < 4; mt++)
                acc[mt] = __builtin_amdgcn_mfma_f32_16x16x32_bf16(al[mt][ks], bh[ks], acc[mt], 0, 0, 0);
        }

        const unsigned chi = (unsigned)code << 16;
#pragma unroll
        for (int mt = 0; mt < 4; mt++) {
#pragma unroll
            for (int reg = 0; reg < 4; reg++) {
                const int sidx = mt * 4 + reg;
                float sc = acc[mt][reg] - cn;
                float ob1 = b1v[sidx], ob2 = b2v[sidx];
                unsigned oi = i12[sidx];
                bool gt1 = sc > ob1;
                bool gt2 = sc > ob2;
                b1v[sidx] = gt1 ? sc : ob1;
                b2v[sidx] = gt1 ? ob1 : (gt2 ? sc : ob2);
                unsigned na = chi | (oi >> 16);
                unsigned nb = (oi & 0xFFFF0000u) | (unsigned)code;
                i12[sidx] = gt1 ? na : (gt2 ? nb : oi);
            }
        }
    }

    // Dump lane candidates: D row (px) = (lane>>4)*4+reg, col (res) = lane&15.
    const int res = lane & 15, quad = lane >> 4;
#pragma unroll
    for (int mt = 0; mt < 4; mt++)
#pragma unroll
        for (int reg = 0; reg < 4; reg++) {
            int px = mt * 16 + quad * 4 + reg;
            int e = (wave * 16 + res) * 64 + px;
            s1l[e] = b1v[mt * 4 + reg];
            s2l[e] = b2v[mt * 4 + reg];
            iil[e] = i12[mt * 4 + reg];
        }
    __syncthreads();

    if (t < 64) {
        float B1 = -1e30f, B2 = -1e30f;
        int   I1 = 0x7fffffff, I2 = 0x7fffffff;
        for (int w = 0; w < 64; w++) {
            int e = w * 64 + t;
            float sA = s1l[e], sB = s2l[e];
            unsigned ii = iil[e];
            int iA = (int)(ii >> 16), iB = (int)(ii & 0xffffu);
            bool a1 = (sA > B1) || (sA == B1 && iA < I1);
            bool a2 = (sA > B2) || (sA == B2 && iA < I2);
            if (a1) { B2 = B1; I2 = I1; B1 = sA; I1 = iA; }
            else if (a2) { B2 = sA; I2 = iA; }
            bool c1 = (sB > B1) || (sB == B1 && iB < I1);
            bool c2 = (sB > B2) || (sB == B2 && iB < I2);
            if (c1) { B2 = B1; I2 = I1; B1 = sB; I1 = iB; }
            else if (c2) { B2 = sB; I2 = iB; }
        }
        const int p = p0 + t;
        pidx2[(split * NP + p) * 2 + 0] = I1;
        pidx2[(split * NP + p) * 2 + 1] = I2;
    }
}

// ---------------------------------------------------------------------------
// K4: exact f64 rescore of 8 candidates/px, pick token (tie -> lowest idx ==
// np.argmin), gather z_q = emb[token] (fp32, (b,e,s) layout).
// ---------------------------------------------------------------------------
__global__ __launch_bounds__(256) void rescore_gather(
    const float* __restrict__ z, const float* __restrict__ emb,
    const int* __restrict__ pidx2, float* __restrict__ out_zq)
{
    __shared__ __align__(16) float zl[64 * 132];
    __shared__ double sc8[64 * 8];
    __shared__ int    id8[64 * 8];
    __shared__ int    tok[64];

    const int t  = threadIdx.x;
    const int p0 = blockIdx.x * 64;
    const int b  = p0 >> 8;
    const int s0 = p0 & 255;

    for (int idx = t; idx < 64 * 128; idx += 256) {
        int k = idx >> 6, i = idx & 63;
        zl[i * 132 + k] = z[(size_t)(b * NE + k) * NS + s0 + i];
    }
    __syncthreads();

    const int i_loc = t >> 2;
    const int c4    = t & 3;
    const int p     = p0 + i_loc;
#pragma unroll
    for (int cc = 0; cc < 2; cc++) {
        int ci = c4 * 2 + cc;        // 0..7
        int split = ci >> 1, slot = ci & 1;
        int idx = pidx2[(split * NP + p) * 2 + slot];
        const float* er = emb + (size_t)idx * NE;
        double dot = 0.0, nn = 0.0;
        for (int k = 0; k < NE; k += 4) {
            float4 e4 = *(const float4*)(er + k);
            dot += (double)zl[i_loc * 132 + k + 0] * (double)e4.x;
            dot += (double)zl[i_loc * 132 + k + 1] * (double)e4.y;
            dot += (double)zl[i_loc * 132 + k + 2] * (double)e4.z;
            dot += (double)zl[i_loc * 132 + k + 3] * (double)e4.w;
            nn  += (double)e4.x * e4.x + (double)e4.y * e4.y
                 + (double)e4.z * e4.z + (double)e4.w * e4.w;
        }
        sc8[i_loc * 8 + ci] = dot - 0.5 * nn;
        id8[i_loc * 8 + ci] = idx;
    }
    __syncthreads();

    if (t < 64) {
        double bs = -1e300; int bi = 0x7fffffff;
        for (int ci = 0; ci < 8; ci++) {
            double sc = sc8[t * 8 + ci]; int ii = id8[t * 8 + ci];
            if (sc > bs || (sc == bs && ii < bi)) { bs = sc; bi = ii; }
        }
        tok[t] = bi;
    }
    __syncthreads();

    for (int idx = t; idx < NE * 64; idx += 256) {
        int e = idx >> 6, i = idx & 63;
        out_zq[(size_t)(b * NE + e) * NS + s0 + i] = emb[(size_t)tok[i] * NE + e];
    }
}

// ---------------------------------------------------------------------------
// K5: rec = post_w @ z_q + post_b (fp32). Writes the entire rec region.
// ---------------------------------------------------------------------------
__global__ __launch_bounds__(256) void post_conv(
    const float* __restrict__ zq, const float* __restrict__ post_w,
    const float* __restrict__ post_b, float* __restrict__ out_rec)
{
    __shared__ __align__(16) float wlds[16 * 128];
    const int t  = threadIdx.x;
    const int c0 = blockIdx.x * 16;
    const int b  = blockIdx.y;

    for (int idx = t; idx < 16 * 128; idx += 256) {
        int r = idx >> 7, e = idx & 127;
        wlds[r * 128 + e] = post_w[(c0 + r) * 128 + e];
    }
    __syncthreads();

    const int s = t;
    float acc[16];
#pragma unroll
    for (int r = 0; r < 16; r++) acc[r] = post_b[c0 + r];

    const float* zin = zq + (size_t)(b * NE) * NS + s;
    for (int e = 0; e < NE; e += 4) {
        float z0 = zin[(e + 0) * NS];
        float z1 = zin[(e + 1) * NS];
        float z2 = zin[(e + 2) * NS];
        float z3 = zin[(e + 3) * NS];
#pragma unroll
        for (int r = 0; r < 16; r++) {
            float4 w = *(const float4*)&wlds[r * 128 + e];
            acc[r] = fmaf(z0, w.x, fmaf(z1, w.y, fmaf(z2, w.z, fmaf(z3, w.w, acc[r]))));
        }
    }
#pragma unroll
    for (int r = 0; r < 16; r++)
        out_rec[(size_t)(b * NC + c0 + r) * NS + s] = acc[r];
}

// ---------------------------------------------------------------------------
extern "C" void kernel_launch(void* const* d_in, const int* in_sizes, int n_in,
                              void* d_out, int out_size, void* d_ws, size_t ws_size,
                              hipStream_t stream)
{
    const float* z_e    = (const float*)d_in[0];  // (32,256,16,16) fp32
    const float* pre_w  = (const float*)d_in[1];  // (128,256) fp32
    const float* pre_b  = (const float*)d_in[2];  // (128) fp32
    const float* emb    = (const float*)d_in[3];  // (4096,128) fp32
    const float* post_w = (const float*)d_in[4];  // (256,128) fp32
    const float* post_b = (const float*)d_in[5];  // (256) fp32

    // d_out: fp32 x 4194304 = (z 1048576 | z_q 1048576 | rec 2097152)
    float* out     = (float*)d_out;
    float* out_z   = out;
    float* out_zq  = out + 1048576;
    float* out_rec = out + 2097152;

    // Scratch: Bpack 2 MB + cnorm 16 KB + pidx2 256 KB = 2,375,680 B.
    // Primary home: d_ws. Fallback (constant per session): rec-region head,
    // consumed before post_conv overwrites it.
    const size_t NEED = (size_t)NV * NE * 2 * 2 + NV * 4 + (size_t)NSPLIT * NP * 2 * 4;
    char* scr = (ws_size >= NEED) ? (char*)d_ws : (char*)out_rec;
    ushort_t* Bpack = (ushort_t*)scr;                 // 1,048,576 ushort (2 MB)
    float*    cnorm = (float*)(scr + 2097152);        // 4096 f32
    int*      pidx2 = (int*)(scr + 2113536);          // 65536 i32

    pre_conv      <<<dim3(8, 32),       256, 0, stream>>>(z_e, pre_w, pre_b, out_z);
    pack_b        <<<dim3(32),          256, 0, stream>>>(emb, Bpack, cnorm);
    score_mfma    <<<dim3(128, NSPLIT), 256, 0, stream>>>(out_z, Bpack, cnorm, pidx2);
    rescore_gather<<<dim3(128),         256, 0, stream>>>(out_z, emb, pidx2, out_zq);
    post_conv     <<<dim3(16, 32),      256, 0, stream>>>(out_zq, post_w, post_b, out_rec);
}

// Round 7
// 177.488 us; speedup vs baseline: 1.5749x; 1.0006x over previous
//
#include <hip/hip_runtime.h>
#include <hip/hip_bf16.h>
#include <cstdint>

// Problem constants
#define NB   32      // batch
#define NC   256     // z channels
#define NE   128     // embed dim
#define NS   256     // H*W pixels per batch
#define NV   4096    // vocab
#define NP   8192    // total pixels
#define NSPLIT 8     // vocab splits (512 codes each)

typedef unsigned short ushort_t;
typedef __attribute__((ext_vector_type(8))) short bf16x8;
typedef __attribute__((ext_vector_type(8))) unsigned short us8;
typedef __attribute__((ext_vector_type(4))) float f32x4;

__device__ __forceinline__ float bf2f(ushort_t u) {
    union { unsigned int i; float f; } x; x.i = ((unsigned int)u) << 16; return x.f;
}
__device__ __forceinline__ ushort_t f2bf(float f) {
    __hip_bfloat16 h = __float2bfloat16(f);
    ushort_t u; __builtin_memcpy(&u, &h, 2); return u;
}
__device__ __forceinline__ unsigned asu(float f) { unsigned u; __builtin_memcpy(&u,&f,4); return u; }
__device__ __forceinline__ float    asf(unsigned u) { float f; __builtin_memcpy(&f,&u,4); return f; }

// ---------------------------------------------------------------------------
// K1 (fused): bx<8 -> pre_conv (z = pre_w @ z_e + pre_b, fp32; weights via
// uniform scalar loads -> s_load, no LDS). Arithmetic order IDENTICAL to the
// validated round-6 kernel => bit-identical z (token stability).
//             bx==8 -> pack emb hi-bf16 into Bpack (MFMA B-frag order) + cnorm.
// Bpack (ushort units): [(G*4 + ks)*512 + L*8 + j],
//   element = emb[code = G*16 + (L&15)][k = ks*32 + (L>>4)*8 + j]
// ---------------------------------------------------------------------------
__global__ __launch_bounds__(256) void pre_conv_pack(
    const float* __restrict__ z_e, const float* __restrict__ pre_w,
    const float* __restrict__ pre_b, const float* __restrict__ emb,
    float* __restrict__ out_z, ushort_t* __restrict__ Bpack,
    float* __restrict__ cnorm)
{
    const int t = threadIdx.x;

    if (blockIdx.x == 8) {     // ---- emb pack + cnorm (32 y-blocks x 128 codes)
        if (t < 128) {
            const int v = blockIdx.y * 128 + t;
            const float* row = emb + (size_t)v * NE;
            const int G = v >> 4;
            float nn = 0.f;
#pragma unroll
            for (int ks = 0; ks < 4; ks++) {
#pragma unroll
                for (int q = 0; q < 4; q++) {
                    us8 hv;
#pragma unroll
                    for (int j = 0; j < 8; j++) {
                        float x = row[ks * 32 + q * 8 + j];
                        nn = fmaf(x, x, nn);
                        hv[j] = f2bf(x);
                    }
                    const int L = (v & 15) | (q << 4);
                    *(us8*)(Bpack + ((size_t)G * 4 + ks) * 512 + L * 8) = hv;
                }
            }
            cnorm[v] = 0.5f * nn;
        }
        return;
    }

    // ---- pre_conv role
    const int e0 = blockIdx.x * 16;
    const int b  = blockIdx.y;
    const int s  = t;

    float acc[16];
#pragma unroll
    for (int r = 0; r < 16; r++) acc[r] = pre_b[e0 + r];   // uniform

    const float* zin = z_e + (size_t)(b * NC) * NS + s;
    for (int c = 0; c < NC; c += 4) {
        float z0 = zin[(c + 0) * NS];
        float z1 = zin[(c + 1) * NS];
        float z2 = zin[(c + 2) * NS];
        float z3 = zin[(c + 3) * NS];
#pragma unroll
        for (int r = 0; r < 16; r++) {
            float4 w = *(const float4*)&pre_w[(e0 + r) * 256 + c];  // uniform -> s_load
            acc[r] = fmaf(z0, w.x, fmaf(z1, w.y, fmaf(z2, w.z, fmaf(z3, w.w, acc[r]))));
        }
    }
#pragma unroll
    for (int r = 0; r < 16; r++)
        out_z[(size_t)(b * NE + e0 + r) * NS + s] = acc[r];
}

// ---------------------------------------------------------------------------
// K2: MFMA score filter, single bf16 term (noise sigma ~1.2e-6 << gap 7e-5).
// Block = 64 px x 512 codes (split); 4 waves x 8 cgi x 16 codes.
// A-frags: fp32->bf16 by bit-truncation from LDS-staged z (trunc is within
// the noise model). Per-lane top-2 over each slot's 8 codes with cgi encoded
// in the low 3 mantissa bits; block-reduce -> top-4 per split -> pidx4.
// Exact f64 rescore of all 8x4=32 candidates happens in K3.
// ---------------------------------------------------------------------------
__global__ __launch_bounds__(256, 3) void score_mfma(
    const float* __restrict__ z, const ushort_t* __restrict__ Bpack,
    const float* __restrict__ cnorm, int* __restrict__ pidx4)
{
    __shared__ __align__(16) char smraw[40960];
    float* As  = (float*)smraw;             // 64*132*4 = 33792 B (staging)
    float* r1  = (float*)smraw;             // 64*65*4  = 16640 B (reduction)
    float* r2  = (float*)(smraw + 16640);   // 16640 B
    float* t4b = (float*)(smraw + 33280);   // 64*4*4*4 = 4096 B

    const int t = threadIdx.x;
    const int wave = t >> 6, lane = t & 63;
    const int set = blockIdx.x;      // 0..127 (64 px each)
    const int split = blockIdx.y;    // 0..7
    const int p0 = set * 64;
    const int b  = p0 >> 8;
    const int s0 = p0 & 255;

    // Stage A tile: 64 px x 128 k fp32 (coalesced along s)
    for (int idx = t; idx < 64 * 128; idx += 256) {
        int k = idx >> 6, i = idx & 63;
        As[i * 132 + k] = z[(size_t)(b * NE + k) * NS + s0 + i];
    }
    __syncthreads();

    // Build A fragments (hi-bf16 by truncation): 4 mtiles x 4 ksteps
    const int am = lane & 15, aq = lane >> 4;
    bf16x8 ah[4][4];
#pragma unroll
    for (int mt = 0; mt < 4; mt++)
#pragma unroll
        for (int ks = 0; ks < 4; ks++) {
            const unsigned* src = (const unsigned*)(As + (mt * 16 + am) * 132 + ks * 32 + aq * 8);
            union { unsigned u[4]; bf16x8 v; } pk;
#pragma unroll
            for (int pr = 0; pr < 4; pr++)
                pk.u[pr] = (src[2 * pr + 1] & 0xFFFF0000u) | (src[2 * pr] >> 16);
            ah[mt][ks] = pk.v;
        }
    __syncthreads();   // all As reads done before LDS reuse

    const int Gbase = split * 32 + wave * 8;
    float cn[8];
#pragma unroll
    for (int cgi = 0; cgi < 8; cgi++)
        cn[cgi] = cnorm[(Gbase + cgi) * 16 + am];

    float b1v[16], b2v[16];
#pragma unroll
    for (int i = 0; i < 16; i++) { b1v[i] = -1e30f; b2v[i] = -1e30f; }

    bf16x8 bh[4], bhn[4];
#pragma unroll
    for (int ks = 0; ks < 4; ks++)
        bh[ks] = *(const bf16x8*)(Bpack + ((size_t)Gbase * 4 + ks) * 512 + lane * 8);

    for (int cgi = 0; cgi < 8; cgi++) {
        if (cgi < 7) {
#pragma unroll
            for (int ks = 0; ks < 4; ks++)
                bhn[ks] = *(const bf16x8*)(Bpack + ((size_t)(Gbase + cgi + 1) * 4 + ks) * 512 + lane * 8);
        }

        f32x4 acc[4];
#pragma unroll
        for (int mt = 0; mt < 4; mt++) acc[mt] = (f32x4){0.f, 0.f, 0.f, 0.f};
#pragma unroll
        for (int ks = 0; ks < 4; ks++)
#pragma unroll
            for (int mt = 0; mt < 4; mt++)
                acc[mt] = __builtin_amdgcn_mfma_f32_16x16x32_bf16(ah[mt][ks], bh[ks], acc[mt], 0, 0, 0);

#pragma unroll
        for (int mt = 0; mt < 4; mt++)
#pragma unroll
            for (int reg = 0; reg < 4; reg++) {
                const int si = mt * 4 + reg;
                float sc = acc[mt][reg] - cn[cgi];
                float ev = asf((asu(sc) & ~7u) | (unsigned)cgi);   // embed cgi
                b2v[si] = fmaxf(b2v[si], fminf(ev, b1v[si]));
                b1v[si] = fmaxf(b1v[si], ev);
            }
#pragma unroll
        for (int ks = 0; ks < 4; ks++) bh[ks] = bhn[ks];
    }

    // Dump per-slot top-2 (slot = wave*16 + res; stride 65 breaks conflicts)
    const int slot = wave * 16 + am;
#pragma unroll
    for (int mt = 0; mt < 4; mt++)
#pragma unroll
        for (int reg = 0; reg < 4; reg++) {
            int px = mt * 16 + aq * 4 + reg;
            r1[slot * 65 + px] = b1v[mt * 4 + reg];
            r2[slot * 65 + px] = b2v[mt * 4 + reg];
        }
    __syncthreads();

    // Chunk scan: thread (px = t>>2, ch = t&3) scans 16 slots (32 entries),
    // re-encodes full in-split identity (9 bits: w[8:7] res[6:3] cgi[2:0]).
    {
        const int px = t >> 2, ch = t & 3;
        float t1 = -1e30f, t2 = -1e30f, t3 = -1e30f, t4 = -1e30f;
        for (int i = 0; i < 16; i++) {
            int sl = ch * 16 + i;
#pragma unroll
            for (int e = 0; e < 2; e++) {
                float raw = e ? r2[sl * 65 + px] : r1[sl * 65 + px];
                unsigned vb = asu(raw);
                float v = asf((vb & ~511u) | ((unsigned)sl << 3) | (vb & 7u));
                t4 = fmaxf(t4, fminf(v, t3));
                t3 = fmaxf(t3, fminf(v, t2));
                t2 = fmaxf(t2, fminf(v, t1));
                t1 = fmaxf(t1, v);
            }
        }
        float* dst = t4b + (px * 4 + ch) * 4;
        dst[0] = t1; dst[1] = t2; dst[2] = t3; dst[3] = t4;
    }
    __syncthreads();

    if (t < 64) {
        float u1 = -1e30f, u2 = -1e30f, u3 = -1e30f, u4 = -1e30f;
        for (int ch = 0; ch < 4; ch++) {
#pragma unroll
            for (int j = 0; j < 4; j++) {
                float v = t4b[(t * 4 + ch) * 4 + j];
                u4 = fmaxf(u4, fminf(v, u3));
                u3 = fmaxf(u3, fminf(v, u2));
                u2 = fmaxf(u2, fminf(v, u1));
                u1 = fmaxf(u1, v);
            }
        }
        const int p = p0 + t;
        float uu[4] = { u1, u2, u3, u4 };
#pragma unroll
        for (int j = 0; j < 4; j++) {
            unsigned bits = asu(uu[j]) & 511u;
            int w = (int)(bits >> 7), res = (int)((bits >> 3) & 15u), cg = (int)(bits & 7u);
            pidx4[((size_t)split * NP + p) * 4 + j] = split * 512 + (w * 8 + cg) * 16 + res;
        }
    }
}

// ---------------------------------------------------------------------------
// K3: exact f64 rescore of the 32 candidates/px, pick token (tie -> lowest
// idx == np.argmin), gather z_q = emb[token] (fp32, (b,e,s) layout).
// Block = 32 px, 256 threads (8 chunks/px, one split's 4 candidates each).
// ---------------------------------------------------------------------------
__global__ __launch_bounds__(256) void rescore_gather(
    const float* __restrict__ z, const float* __restrict__ emb,
    const int* __restrict__ pidx4, float* __restrict__ out_zq)
{
    __shared__ __align__(16) float zl[32 * 132];
    __shared__ double bsl[32 * 8];
    __shared__ int    bil[32 * 8];
    __shared__ int    tok[32];

    const int t  = threadIdx.x;
    const int p0 = blockIdx.x * 32;
    const int b  = p0 >> 8;
    const int s0 = p0 & 255;

    for (int idx = t; idx < 32 * 128; idx += 256) {
        int k = idx >> 5, i = idx & 31;
        zl[i * 132 + k] = z[(size_t)(b * NE + k) * NS + s0 + i];
    }
    __syncthreads();

    const int il = t >> 3;   // px local 0..31
    const int ch = t & 7;    // split 0..7
    const int p  = p0 + il;
    double bs = -1e300; int bi = 0x7fffffff;
#pragma unroll
    for (int j = 0; j < 4; j++) {
        int idx = pidx4[((size_t)ch * NP + p) * 4 + j];
        const float* er = emb + (size_t)idx * NE;
        double dot = 0.0, nn = 0.0;
        for (int k = 0; k < NE; k += 4) {
            float4 e4 = *(const float4*)(er + k);
            dot += (double)zl[il * 132 + k + 0] * (double)e4.x;
            dot += (double)zl[il * 132 + k + 1] * (double)e4.y;
            dot += (double)zl[il * 132 + k + 2] * (double)e4.z;
            dot += (double)zl[il * 132 + k + 3] * (double)e4.w;
            nn  += (double)e4.x * e4.x + (double)e4.y * e4.y
                 + (double)e4.z * e4.z + (double)e4.w * e4.w;
        }
        double sc = dot - 0.5 * nn;
        if (sc > bs || (sc == bs && idx < bi)) { bs = sc; bi = idx; }
    }
    bsl[il * 8 + ch] = bs;
    bil[il * 8 + ch] = bi;
    __syncthreads();

    if (t < 32) {
        double B = -1e300; int I = 0x7fffffff;
        for (int c = 0; c < 8; c++) {
            double sc = bsl[t * 8 + c]; int ii = bil[t * 8 + c];
            if (sc > B || (sc == B && ii < I)) { B = sc; I = ii; }
        }
        tok[t] = I;
    }
    __syncthreads();

    for (int idx = t; idx < NE * 32; idx += 256) {
        int e = idx >> 5, i = idx & 31;
        out_zq[(size_t)(b * NE + e) * NS + s0 + i] = emb[(size_t)tok[i] * NE + e];
    }
}

// ---------------------------------------------------------------------------
// K4: rec = post_w @ z_q + post_b (fp32, uniform scalar weight loads).
// Identical fmaf chain to round 6 => bit-identical rec. Overwrites scratch.
// ---------------------------------------------------------------------------
__global__ __launch_bounds__(256) void post_conv(
    const float* __restrict__ zq, const float* __restrict__ post_w,
    const float* __restrict__ post_b, float* __restrict__ out_rec)
{
    const int t  = threadIdx.x;
    const int c0 = blockIdx.x * 16;
    const int b  = blockIdx.y;
    const int s  = t;

    float acc[16];
#pragma unroll
    for (int r = 0; r < 16; r++) acc[r] = post_b[c0 + r];

    const float* zin = zq + (size_t)(b * NE) * NS + s;
    for (int e = 0; e < NE; e += 4) {
        float z0 = zin[(e + 0) * NS];
        float z1 = zin[(e + 1) * NS];
        float z2 = zin[(e + 2) * NS];
        float z3 = zin[(e + 3) * NS];
#pragma unroll
        for (int r = 0; r < 16; r++) {
            float4 w = *(const float4*)&post_w[(c0 + r) * 128 + e];  // uniform -> s_load
            acc[r] = fmaf(z0, w.x, fmaf(z1, w.y, fmaf(z2, w.z, fmaf(z3, w.w, acc[r]))));
        }
    }
#pragma unroll
    for (int r = 0; r < 16; r++)
        out_rec[(size_t)(b * NC + c0 + r) * NS + s] = acc[r];
}

// ---------------------------------------------------------------------------
extern "C" void kernel_launch(void* const* d_in, const int* in_sizes, int n_in,
                              void* d_out, int out_size, void* d_ws, size_t ws_size,
                              hipStream_t stream)
{
    const float* z_e    = (const float*)d_in[0];
    const float* pre_w  = (const float*)d_in[1];
    const float* pre_b  = (const float*)d_in[2];
    const float* emb    = (const float*)d_in[3];
    const float* post_w = (const float*)d_in[4];
    const float* post_b = (const float*)d_in[5];

    // d_out: fp32 x 4194304 = (z 1048576 | z_q 1048576 | rec 2097152)
    float* out     = (float*)d_out;
    float* out_z   = out;
    float* out_zq  = out + 1048576;
    float* out_rec = out + 2097152;

    // Scratch: Bpack 1 MB + cnorm 16 KB + pidx4 1 MB = 2,113,536 B.
    // Primary: d_ws; fallback (constant per session): rec-region head,
    // fully consumed before post_conv overwrites it.
    const size_t SZ_BPACK = (size_t)256 * 4 * 512 * 2;            // 1 MB
    const size_t SZ_CNORM = (size_t)NV * 4;                       // 16 KB
    const size_t SZ_PIDX4 = (size_t)NSPLIT * NP * 4 * 4;          // 1 MB
    const size_t NEED = SZ_BPACK + SZ_CNORM + SZ_PIDX4;
    char* scr = (ws_size >= NEED) ? (char*)d_ws : (char*)out_rec;
    ushort_t* Bpack = (ushort_t*)scr;
    float*    cnorm = (float*)(scr + SZ_BPACK);
    int*      pidx4 = (int*)(scr + SZ_BPACK + SZ_CNORM);

    pre_conv_pack <<<dim3(9, 32),        256, 0, stream>>>(z_e, pre_w, pre_b, emb,
                                                           out_z, Bpack, cnorm);
    score_mfma    <<<dim3(128, NSPLIT),  256, 0, stream>>>(out_z, Bpack, cnorm, pidx4);
    rescore_gather<<<dim3(256),          256, 0, stream>>>(out_z, emb, pidx4, out_zq);
    post_conv     <<<dim3(16, 32),       256, 0, stream>>>(out_zq, post_w, post_b, out_rec);
}

// Round 8
// 152.536 us; speedup vs baseline: 1.8326x; 1.1636x over previous
//
#include <hip/hip_runtime.h>
#include <hip/hip_bf16.h>
#include <cstdint>

// Problem constants
#define NB   32      // batch
#define NC   256     // z channels
#define NE   128     // embed dim
#define NS   256     // H*W pixels per batch
#define NV   4096    // vocab
#define NP   8192    // total pixels
#define NSPLIT 8     // vocab splits (512 codes each)

typedef unsigned short ushort_t;
typedef __attribute__((ext_vector_type(8))) short bf16x8;
typedef __attribute__((ext_vector_type(8))) unsigned short us8;
typedef __attribute__((ext_vector_type(4))) float f32x4;

__device__ __forceinline__ float bf2f(ushort_t u) {
    union { unsigned int i; float f; } x; x.i = ((unsigned int)u) << 16; return x.f;
}
__device__ __forceinline__ ushort_t f2bf(float f) {
    __hip_bfloat16 h = __float2bfloat16(f);
    ushort_t u; __builtin_memcpy(&u, &h, 2); return u;
}
__device__ __forceinline__ unsigned asu(float f) { unsigned u; __builtin_memcpy(&u,&f,4); return u; }
__device__ __forceinline__ float    asf(unsigned u) { float f; __builtin_memcpy(&f,&u,4); return f; }

// ---------------------------------------------------------------------------
// K1 (fused):
//  bx<8  -> pre_conv: z = pre_w @ z_e + pre_b. Grid (8 e-tiles, 32 b, 4 s-blk)
//           = 1024 blocks; LDS-staged weights; k split 4 ways across waves
//           (16-step dependent chains); LDS partial-sum reduction.
//  bx==8 -> pack emb hi-bf16 into Bpack (MFMA B-frag order) + cnorm.
//           128 blocks (by,bz) x 32 codes, 8 lanes/code, shfl norm-reduce.
// Bpack (ushort units): [(G*4 + ks)*512 + L*8 + j],
//   element = emb[code = G*16 + (L&15)][k = ks*32 + (L>>4)*8 + j]
// ---------------------------------------------------------------------------
__global__ __launch_bounds__(256) void pre_conv_pack(
    const float* __restrict__ z_e, const float* __restrict__ pre_w,
    const float* __restrict__ pre_b, const float* __restrict__ emb,
    float* __restrict__ out_z, ushort_t* __restrict__ Bpack,
    float* __restrict__ cnorm)
{
    __shared__ __align__(16) float wtile[16 * 256];   // 16 KB
    __shared__ __align__(16) float part[4 * 16 * 64]; // 16 KB

    const int t = threadIdx.x;

    if (blockIdx.x == 8) {   // ---- pack role
        const int v     = (blockIdx.y * 4 + blockIdx.z) * 32 + (t >> 3);
        const int chunk = t & 7;
        const float4* rp = (const float4*)(emb + (size_t)v * NE + chunk * 16);
        float4 x0 = rp[0], x1 = rp[1], x2 = rp[2], x3 = rp[3];
        float xs[16] = { x0.x, x0.y, x0.z, x0.w, x1.x, x1.y, x1.z, x1.w,
                         x2.x, x2.y, x2.z, x2.w, x3.x, x3.y, x3.z, x3.w };
        us8 h0, h1;
        float nn = 0.f;
#pragma unroll
        for (int j = 0; j < 8; j++) {
            nn = fmaf(xs[j], xs[j], nn);
            h0[j] = f2bf(xs[j]);
        }
#pragma unroll
        for (int j = 0; j < 8; j++) {
            nn = fmaf(xs[8 + j], xs[8 + j], nn);
            h1[j] = f2bf(xs[8 + j]);
        }
        nn += __shfl_xor(nn, 1);
        nn += __shfl_xor(nn, 2);
        nn += __shfl_xor(nn, 4);
        if (chunk == 0) cnorm[v] = 0.5f * nn;

        const int G  = v >> 4;
        const int ks = chunk >> 1;
        const int q0 = (chunk & 1) * 2;
        const int L0 = (v & 15) | (q0 << 4);
        const int L1 = (v & 15) | ((q0 + 1) << 4);
        *(us8*)(Bpack + ((size_t)G * 4 + ks) * 512 + L0 * 8) = h0;
        *(us8*)(Bpack + ((size_t)G * 4 + ks) * 512 + L1 * 8) = h1;
        return;
    }

    // ---- pre_conv role
    const int e0 = blockIdx.x * 16;
    const int b  = blockIdx.y;
    const int s0 = blockIdx.z * 64;

    for (int idx = t; idx < 16 * 256; idx += 256)
        wtile[idx] = pre_w[(e0 + (idx >> 8)) * 256 + (idx & 255)];
    __syncthreads();

    const int kq = t >> 6, sl = t & 63;
    float acc[16];
#pragma unroll
    for (int r = 0; r < 16; r++) acc[r] = 0.f;

    const float* zin = z_e + (size_t)(b * NC + kq * 64) * NS + s0 + sl;
    const int cb = kq * 64;
#pragma unroll 4
    for (int i = 0; i < 16; i++) {
        const int c = i * 4;
        float z0 = zin[(c + 0) * NS];
        float z1 = zin[(c + 1) * NS];
        float z2 = zin[(c + 2) * NS];
        float z3 = zin[(c + 3) * NS];
#pragma unroll
        for (int r = 0; r < 16; r++) {
            float4 w = *(const float4*)&wtile[r * 256 + cb + c];
            acc[r] = fmaf(z0, w.x, fmaf(z1, w.y, fmaf(z2, w.z, fmaf(z3, w.w, acc[r]))));
        }
    }
#pragma unroll
    for (int r = 0; r < 16; r++)
        part[(kq * 16 + r) * 64 + sl] = acc[r];
    __syncthreads();

    const int r4 = t >> 6, sl2 = t & 63;
#pragma unroll
    for (int j = 0; j < 4; j++) {
        const int r = j * 4 + r4;
        float v = pre_b[e0 + r]
                + part[(0 * 16 + r) * 64 + sl2]
                + part[(1 * 16 + r) * 64 + sl2]
                + part[(2 * 16 + r) * 64 + sl2]
                + part[(3 * 16 + r) * 64 + sl2];
        out_z[(size_t)(b * NE + e0 + r) * NS + s0 + sl2] = v;
    }
}

// ---------------------------------------------------------------------------
// K2: MFMA score filter (validated round 7, unchanged). Single bf16 term;
// per-lane top-2 per 8-code slot; block top-4 per split -> pidx4.
// ---------------------------------------------------------------------------
__global__ __launch_bounds__(256, 3) void score_mfma(
    const float* __restrict__ z, const ushort_t* __restrict__ Bpack,
    const float* __restrict__ cnorm, int* __restrict__ pidx4)
{
    __shared__ __align__(16) char smraw[40960];
    float* As  = (float*)smraw;             // 64*132*4 = 33792 B (staging)
    float* r1  = (float*)smraw;             // 64*65*4  = 16640 B (reduction)
    float* r2  = (float*)(smraw + 16640);   // 16640 B
    float* t4b = (float*)(smraw + 33280);   // 4096 B

    const int t = threadIdx.x;
    const int wave = t >> 6, lane = t & 63;
    const int set = blockIdx.x;      // 0..127
    const int split = blockIdx.y;    // 0..7
    const int p0 = set * 64;
    const int b  = p0 >> 8;
    const int s0 = p0 & 255;

    for (int idx = t; idx < 64 * 128; idx += 256) {
        int k = idx >> 6, i = idx & 63;
        As[i * 132 + k] = z[(size_t)(b * NE + k) * NS + s0 + i];
    }
    __syncthreads();

    const int am = lane & 15, aq = lane >> 4;
    bf16x8 ah[4][4];
#pragma unroll
    for (int mt = 0; mt < 4; mt++)
#pragma unroll
        for (int ks = 0; ks < 4; ks++) {
            const unsigned* src = (const unsigned*)(As + (mt * 16 + am) * 132 + ks * 32 + aq * 8);
            union { unsigned u[4]; bf16x8 v; } pk;
#pragma unroll
            for (int pr = 0; pr < 4; pr++)
                pk.u[pr] = (src[2 * pr + 1] & 0xFFFF0000u) | (src[2 * pr] >> 16);
            ah[mt][ks] = pk.v;
        }
    __syncthreads();

    const int Gbase = split * 32 + wave * 8;
    float cn[8];
#pragma unroll
    for (int cgi = 0; cgi < 8; cgi++)
        cn[cgi] = cnorm[(Gbase + cgi) * 16 + am];

    float b1v[16], b2v[16];
#pragma unroll
    for (int i = 0; i < 16; i++) { b1v[i] = -1e30f; b2v[i] = -1e30f; }

    bf16x8 bh[4], bhn[4];
#pragma unroll
    for (int ks = 0; ks < 4; ks++)
        bh[ks] = *(const bf16x8*)(Bpack + ((size_t)Gbase * 4 + ks) * 512 + lane * 8);

    for (int cgi = 0; cgi < 8; cgi++) {
        if (cgi < 7) {
#pragma unroll
            for (int ks = 0; ks < 4; ks++)
                bhn[ks] = *(const bf16x8*)(Bpack + ((size_t)(Gbase + cgi + 1) * 4 + ks) * 512 + lane * 8);
        }

        f32x4 acc[4];
#pragma unroll
        for (int mt = 0; mt < 4; mt++) acc[mt] = (f32x4){0.f, 0.f, 0.f, 0.f};
#pragma unroll
        for (int ks = 0; ks < 4; ks++)
#pragma unroll
            for (int mt = 0; mt < 4; mt++)
                acc[mt] = __builtin_amdgcn_mfma_f32_16x16x32_bf16(ah[mt][ks], bh[ks], acc[mt], 0, 0, 0);

#pragma unroll
        for (int mt = 0; mt < 4; mt++)
#pragma unroll
            for (int reg = 0; reg < 4; reg++) {
                const int si = mt * 4 + reg;
                float sc = acc[mt][reg] - cn[cgi];
                float ev = asf((asu(sc) & ~7u) | (unsigned)cgi);
                b2v[si] = fmaxf(b2v[si], fminf(ev, b1v[si]));
                b1v[si] = fmaxf(b1v[si], ev);
            }
#pragma unroll
        for (int ks = 0; ks < 4; ks++) bh[ks] = bhn[ks];
    }

    const int slot = wave * 16 + am;
#pragma unroll
    for (int mt = 0; mt < 4; mt++)
#pragma unroll
        for (int reg = 0; reg < 4; reg++) {
            int px = mt * 16 + aq * 4 + reg;
            r1[slot * 65 + px] = b1v[mt * 4 + reg];
            r2[slot * 65 + px] = b2v[mt * 4 + reg];
        }
    __syncthreads();

    {
        const int px = t >> 2, ch = t & 3;
        float t1 = -1e30f, t2 = -1e30f, t3 = -1e30f, t4 = -1e30f;
        for (int i = 0; i < 16; i++) {
            int sl = ch * 16 + i;
#pragma unroll
            for (int e = 0; e < 2; e++) {
                float raw = e ? r2[sl * 65 + px] : r1[sl * 65 + px];
                unsigned vb = asu(raw);
                float v = asf((vb & ~511u) | ((unsigned)sl << 3) | (vb & 7u));
                t4 = fmaxf(t4, fminf(v, t3));
                t3 = fmaxf(t3, fminf(v, t2));
                t2 = fmaxf(t2, fminf(v, t1));
                t1 = fmaxf(t1, v);
            }
        }
        float* dst = t4b + (px * 4 + ch) * 4;
        dst[0] = t1; dst[1] = t2; dst[2] = t3; dst[3] = t4;
    }
    __syncthreads();

    if (t < 64) {
        float u1 = -1e30f, u2 = -1e30f, u3 = -1e30f, u4 = -1e30f;
        for (int ch = 0; ch < 4; ch++) {
#pragma unroll
            for (int j = 0; j < 4; j++) {
                float v = t4b[(t * 4 + ch) * 4 + j];
                u4 = fmaxf(u4, fminf(v, u3));
                u3 = fmaxf(u3, fminf(v, u2));
                u2 = fmaxf(u2, fminf(v, u1));
                u1 = fmaxf(u1, v);
            }
        }
        const int p = p0 + t;
        float uu[4] = { u1, u2, u3, u4 };
#pragma unroll
        for (int j = 0; j < 4; j++) {
            unsigned bits = asu(uu[j]) & 511u;
            int w = (int)(bits >> 7), res = (int)((bits >> 3) & 15u), cg = (int)(bits & 7u);
            pidx4[((size_t)split * NP + p) * 4 + j] = split * 512 + (w * 8 + cg) * 16 + res;
        }
    }
}

// ---------------------------------------------------------------------------
// K3: exact f64 rescore of the 32 candidates/px, pick token (tie -> lowest
// idx == np.argmin), gather z_q = emb[token]. 512 blocks x 16 px,
// 16 threads/px (2 candidates each).
// ---------------------------------------------------------------------------
__global__ __launch_bounds__(256) void rescore_gather(
    const float* __restrict__ z, const float* __restrict__ emb,
    const int* __restrict__ pidx4, float* __restrict__ out_zq)
{
    __shared__ __align__(16) float zl[16 * 132];
    __shared__ double bsl[16 * 16];
    __shared__ int    bil[16 * 16];
    __shared__ int    tok[16];

    const int t  = threadIdx.x;
    const int p0 = blockIdx.x * 16;
    const int b  = p0 >> 8;
    const int s0 = p0 & 255;

    for (int idx = t; idx < 16 * 128; idx += 256) {
        int k = idx >> 4, i = idx & 15;
        zl[i * 132 + k] = z[(size_t)(b * NE + k) * NS + s0 + i];
    }
    __syncthreads();

    const int il = t >> 4;   // px local 0..15
    const int cc = t & 15;   // candidate pair 0..15
    const int p  = p0 + il;
    double bs = -1e300; int bi = 0x7fffffff;
#pragma unroll
    for (int jj = 0; jj < 2; jj++) {
        int cand = cc * 2 + jj;              // 0..31
        int split = cand >> 2, slot = cand & 3;
        int idx = pidx4[((size_t)split * NP + p) * 4 + slot];
        const float* er = emb + (size_t)idx * NE;
        double dot = 0.0, nn = 0.0;
        for (int k = 0; k < NE; k += 4) {
            float4 e4 = *(const float4*)(er + k);
            dot += (double)zl[il * 132 + k + 0] * (double)e4.x;
            dot += (double)zl[il * 132 + k + 1] * (double)e4.y;
            dot += (double)zl[il * 132 + k + 2] * (double)e4.z;
            dot += (double)zl[il * 132 + k + 3] * (double)e4.w;
            nn  += (double)e4.x * e4.x + (double)e4.y * e4.y
                 + (double)e4.z * e4.z + (double)e4.w * e4.w;
        }
        double sc = dot - 0.5 * nn;
        if (sc > bs || (sc == bs && idx < bi)) { bs = sc; bi = idx; }
    }
    bsl[il * 16 + cc] = bs;
    bil[il * 16 + cc] = bi;
    __syncthreads();

    if (t < 16) {
        double B = -1e300; int I = 0x7fffffff;
        for (int c = 0; c < 16; c++) {
            double sc = bsl[t * 16 + c]; int ii = bil[t * 16 + c];
            if (sc > B || (sc == B && ii < I)) { B = sc; I = ii; }
        }
        tok[t] = I;
    }
    __syncthreads();

    for (int idx = t; idx < NE * 16; idx += 256) {
        int e = idx >> 4, i = idx & 15;
        out_zq[(size_t)(b * NE + e) * NS + s0 + i] = emb[(size_t)tok[i] * NE + e];
    }
}

// ---------------------------------------------------------------------------
// K4: rec = post_w @ z_q + post_b. Grid (16 c-tiles, 32 b, 4 s-blk) = 2048
// blocks; LDS weights; k split 4 ways (8-step chains); LDS reduction.
// Overwrites the scratch region last.
// ---------------------------------------------------------------------------
__global__ __launch_bounds__(256) void post_conv(
    const float* __restrict__ zq, const float* __restrict__ post_w,
    const float* __restrict__ post_b, float* __restrict__ out_rec)
{
    __shared__ __align__(16) float wtile[16 * 128];   // 8 KB
    __shared__ __align__(16) float part[4 * 16 * 64]; // 16 KB

    const int t  = threadIdx.x;
    const int c0 = blockIdx.x * 16;
    const int b  = blockIdx.y;
    const int s0 = blockIdx.z * 64;

    for (int idx = t; idx < 16 * 128; idx += 256)
        wtile[idx] = post_w[(c0 + (idx >> 7)) * 128 + (idx & 127)];
    __syncthreads();

    const int kq = t >> 6, sl = t & 63;
    float acc[16];
#pragma unroll
    for (int r = 0; r < 16; r++) acc[r] = 0.f;

    const float* zin = zq + (size_t)(b * NE + kq * 32) * NS + s0 + sl;
    const int eb = kq * 32;
#pragma unroll 4
    for (int i = 0; i < 8; i++) {
        const int e = i * 4;
        float z0 = zin[(e + 0) * NS];
        float z1 = zin[(e + 1) * NS];
        float z2 = zin[(e + 2) * NS];
        float z3 = zin[(e + 3) * NS];
#pragma unroll
        for (int r = 0; r < 16; r++) {
            float4 w = *(const float4*)&wtile[r * 128 + eb + e];
            acc[r] = fmaf(z0, w.x, fmaf(z1, w.y, fmaf(z2, w.z, fmaf(z3, w.w, acc[r]))));
        }
    }
#pragma unroll
    for (int r = 0; r < 16; r++)
        part[(kq * 16 + r) * 64 + sl] = acc[r];
    __syncthreads();

    const int r4 = t >> 6, sl2 = t & 63;
#pragma unroll
    for (int j = 0; j < 4; j++) {
        const int r = j * 4 + r4;
        float v = post_b[c0 + r]
                + part[(0 * 16 + r) * 64 + sl2]
                + part[(1 * 16 + r) * 64 + sl2]
                + part[(2 * 16 + r) * 64 + sl2]
                + part[(3 * 16 + r) * 64 + sl2];
        out_rec[(size_t)(b * NC + c0 + r) * NS + s0 + sl2] = v;
    }
}

// ---------------------------------------------------------------------------
extern "C" void kernel_launch(void* const* d_in, const int* in_sizes, int n_in,
                              void* d_out, int out_size, void* d_ws, size_t ws_size,
                              hipStream_t stream)
{
    const float* z_e    = (const float*)d_in[0];
    const float* pre_w  = (const float*)d_in[1];
    const float* pre_b  = (const float*)d_in[2];
    const float* emb    = (const float*)d_in[3];
    const float* post_w = (const float*)d_in[4];
    const float* post_b = (const float*)d_in[5];

    // d_out: fp32 x 4194304 = (z 1048576 | z_q 1048576 | rec 2097152)
    float* out     = (float*)d_out;
    float* out_z   = out;
    float* out_zq  = out + 1048576;
    float* out_rec = out + 2097152;

    // Scratch: Bpack 1 MB + cnorm 16 KB + pidx4 1 MB. Primary: d_ws;
    // fallback (constant per session): rec-region head, consumed pre-K4.
    const size_t SZ_BPACK = (size_t)256 * 4 * 512 * 2;            // 1 MB
    const size_t SZ_CNORM = (size_t)NV * 4;                       // 16 KB
    const size_t SZ_PIDX4 = (size_t)NSPLIT * NP * 4 * 4;          // 1 MB
    const size_t NEED = SZ_BPACK + SZ_CNORM + SZ_PIDX4;
    char* scr = (ws_size >= NEED) ? (char*)d_ws : (char*)out_rec;
    ushort_t* Bpack = (ushort_t*)scr;
    float*    cnorm = (float*)(scr + SZ_BPACK);
    int*      pidx4 = (int*)(scr + SZ_BPACK + SZ_CNORM);

    pre_conv_pack <<<dim3(9, 32, 4),     256, 0, stream>>>(z_e, pre_w, pre_b, emb,
                                                           out_z, Bpack, cnorm);
    score_mfma    <<<dim3(128, NSPLIT),  256, 0, stream>>>(out_z, Bpack, cnorm, pidx4);
    rescore_gather<<<dim3(512),          256, 0, stream>>>(out_z, emb, pidx4, out_zq);
    post_conv     <<<dim3(16, 32, 4),    256, 0, stream>>>(out_zq, post_w, post_b, out_rec);
}